// Round 9
// baseline (32.285 us; speedup 1.0000x reference)
//
#include <hip/hip_runtime.h>

// EdgeConv2d: B=4, C=64, N=8192, K=16, C_OUT=64
// out[b,o,n] = relu( max_k ( y1[b, i1(b,n,k), o] + y2[b, i0(b,n,k), o] ) + bias[o] )
// y1 = (W[:,:C] - W[:,C:]) @ x[b],  y2 = W[:,C:] @ x[b]
// y (fp16): y[b][n][s], s<64 -> y1[s], s>=64 -> y2[s-64]. Row = 256 B.
// GEMM: fp16 LDS operands, k-pair interleaved, v_dot2_f32_f16 (round-8).
// Gather v4: dwordx4 lanes, 8 lanes/half-row, 8 lines/instr, 4 instr/node,
// k-max via shfl_xor butterfly. 4x fewer gather instructions than round 4.

#define BB   4
#define CCH  64
#define NN   8192
#define KK   16

typedef _Float16 h2  __attribute__((ext_vector_type(2)));
typedef _Float16 h8  __attribute__((ext_vector_type(8)));
typedef _Float16 h16 __attribute__((ext_vector_type(16)));
typedef int      v4i __attribute__((ext_vector_type(4)));

#if __has_builtin(__builtin_amdgcn_fdot2)
#define FDOT2(a, b, c) __builtin_amdgcn_fdot2((a), (b), (c), false)
#else
#define FDOT2(a, b, c) ((c) + (float)(a).x * (float)(b).x + (float)(a).y * (float)(b).y)
#endif

// ---------------------------------------------------------------------------
// Kernel 1: y GEMM (unchanged from round 8).
// ---------------------------------------------------------------------------
__global__ __launch_bounds__(256) void gemm_kernel(const float* __restrict__ x,
                                                   const float* __restrict__ W,
                                                   _Float16* __restrict__ y) {
    __shared__ _Float16 wT2[32 * 264];   // [kp][2s+p], s = 0..127 stacked chans
    __shared__ _Float16 xs2[32 * 264];   // [kp][2n+p], n = 0..127

    const int t   = threadIdx.x;
    const int blk = blockIdx.x;           // 256 = b(4) x ntile(64)
    const int b   = blk >> 6;
    const int n0  = (blk & 63) * 128;

    {
        const int k  = t & 63;
        const int kp = k >> 1, par = k & 1;
        const int sb = t >> 6;
        #pragma unroll
        for (int i = 0; i < 32; ++i) {
            const int s = sb + 4 * i;
            float v;
            if (s < CCH) v = W[s * 128 + k] - W[s * 128 + 64 + k];
            else         v = W[(s - CCH) * 128 + 64 + k];
            wT2[kp * 264 + 2 * s + par] = (_Float16)v;
        }
    }
    {
        const float* xb = x + (size_t)b * CCH * NN + n0;
        #pragma unroll
        for (int i = 0; i < 8; ++i) {
            const int k  = (t >> 5) + 8 * i;
            const int nq = (t & 31) * 4;
            const float4 v = *(const float4*)&xb[(size_t)k * NN + nq];
            const int kp = k >> 1, par = k & 1;
            _Float16* d = &xs2[kp * 264 + 2 * nq + par];
            d[0] = (_Float16)v.x; d[2] = (_Float16)v.y;
            d[4] = (_Float16)v.z; d[6] = (_Float16)v.w;
        }
    }
    __syncthreads();

    const int sg = t & 15;
    const int ng = t >> 4;
    const int s0 = sg * 8, nn0 = ng * 8;

    float acc[8][8];
    #pragma unroll
    for (int i = 0; i < 8; ++i)
        #pragma unroll
        for (int j = 0; j < 8; ++j) acc[i][j] = 0.f;

    #pragma unroll 2
    for (int kp = 0; kp < 32; ++kp) {
        const h16 wv = *(const h16*)&wT2[kp * 264 + 2 * s0];
        const h16 xv = *(const h16*)&xs2[kp * 264 + 2 * nn0];
        #pragma unroll
        for (int i = 0; i < 8; ++i) {
            h2 wp; wp.x = wv[2 * i]; wp.y = wv[2 * i + 1];
            #pragma unroll
            for (int j = 0; j < 8; ++j) {
                h2 xp; xp.x = xv[2 * j]; xp.y = xv[2 * j + 1];
                acc[i][j] = FDOT2(wp, xp, acc[i][j]);
            }
        }
    }

    _Float16* yb = y + ((size_t)b * NN + n0 + nn0) * 128 + s0;
    #pragma unroll
    for (int j = 0; j < 8; ++j) {
        h8 v;
        #pragma unroll
        for (int i = 0; i < 8; ++i) v[i] = (_Float16)acc[i][j];
        *(h8*)&yb[(size_t)j * 128] = v;
    }
}

// ---------------------------------------------------------------------------
// Kernel 2: gather v4. 1024 blocks x 256 thr; block = (b, 32-node tile).
// Wave owns 8 nodes; per node 4 dwordx4 gathers (lane = kgroup x chanslot),
// butterfly k-max, bias+relu, LDS-transposed coalesced store.
// ---------------------------------------------------------------------------
__global__ __launch_bounds__(256) void gather_kernel(const _Float16* __restrict__ y,
                                                     const int* __restrict__ edge,
                                                     const float* __restrict__ bias,
                                                     float* __restrict__ out) {
    __shared__ int   eL[32][2][16];   // [node][src][k], 4 KB
    __shared__ float sm[32][68];      // [node][chan], pad 68 (16B-aligned rows)

    const int t   = threadIdx.x;
    const int blk = blockIdx.x;       // 1024 = b(4) x tile(256)
    const int b   = blk >> 8;
    const int n0  = (blk & 255) * 32;

    // Stage edge rows: 1024 ints, one int4 per thread, coalesced per src.
    {
        const int e   = t << 2;
        const int n   = e >> 5;
        const int src = (e >> 4) & 1;
        const int k0  = e & 15;
        const size_t ebase = (size_t)(src == 0 ? BB + b : b) * NN * KK;
        *(v4i*)&eL[n][src][k0] = *(const v4i*)&edge[ebase + (size_t)(n0 + n) * KK + k0];
    }
    __syncthreads();

    const int w    = t >> 6;          // wave 0..3 -> nodes 8w..8w+7
    const int lane = t & 63;
    const int kg   = lane >> 3;       // k-group 0..7
    const int cs   = lane & 7;        // chan-slot: chans 8cs..8cs+7

    const _Float16* yb = y + (size_t)b * NN * 128;
    const float4 bv0 = *(const float4*)&bias[cs * 8];
    const float4 bv1 = *(const float4*)&bias[cs * 8 + 4];

    #pragma unroll
    for (int batch = 0; batch < 2; ++batch) {
        h8 a1[4], a2[4], c1[4], c2[4];
        // Issue all 16 gathers (independent -> deep MLP).
        #pragma unroll
        for (int u = 0; u < 4; ++u) {
            const int nn  = w * 8 + batch * 4 + u;
            const int i1a = eL[nn][0][kg];
            const int i1b = eL[nn][0][kg + 8];
            const int i0a = eL[nn][1][kg];
            const int i0b = eL[nn][1][kg + 8];
            a1[u] = *(const h8*)&yb[(size_t)i1a * 128 + cs * 8];        // y1, k=kg
            a2[u] = *(const h8*)&yb[(size_t)i1b * 128 + cs * 8];        // y1, k=kg+8
            c1[u] = *(const h8*)&yb[(size_t)i0a * 128 + 64 + cs * 8];   // y2, k=kg
            c2[u] = *(const h8*)&yb[(size_t)i0b * 128 + 64 + cs * 8];   // y2, k=kg+8
        }
        #pragma unroll
        for (int u = 0; u < 4; ++u) {
            const int nn = w * 8 + batch * 4 + u;
            union { h8 v; int i[4]; } um, ut;
            um.v = __builtin_elementwise_max(a1[u] + c1[u], a2[u] + c2[u]);
            #pragma unroll
            for (int s = 8; s < 64; s <<= 1) {
                #pragma unroll
                for (int r = 0; r < 4; ++r) ut.i[r] = __shfl_xor(um.i[r], s, 64);
                um.v = __builtin_elementwise_max(um.v, ut.v);
            }
            if (kg == 0) {       // lanes 0..7 hold the final max for their slice
                float4 ra, rb;
                ra.x = fmaxf((float)um.v[0] + bv0.x, 0.f);
                ra.y = fmaxf((float)um.v[1] + bv0.y, 0.f);
                ra.z = fmaxf((float)um.v[2] + bv0.z, 0.f);
                ra.w = fmaxf((float)um.v[3] + bv0.w, 0.f);
                rb.x = fmaxf((float)um.v[4] + bv1.x, 0.f);
                rb.y = fmaxf((float)um.v[5] + bv1.y, 0.f);
                rb.z = fmaxf((float)um.v[6] + bv1.z, 0.f);
                rb.w = fmaxf((float)um.v[7] + bv1.w, 0.f);
                *(float4*)&sm[nn][cs * 8]     = ra;
                *(float4*)&sm[nn][cs * 8 + 4] = rb;
            }
        }
    }
    __syncthreads();

    // Transposed coalesced stores: 64 chans x 8 n-quads = 512 pairs, 2/thread.
    #pragma unroll
    for (int r2 = 0; r2 < 2; ++r2) {
        const int idx = t + (r2 << 8);    // 0..511
        const int c   = idx >> 3;         // 0..63
        const int q   = idx & 7;          // 0..7
        float4 v;
        v.x = sm[4 * q + 0][c];
        v.y = sm[4 * q + 1][c];
        v.z = sm[4 * q + 2][c];
        v.w = sm[4 * q + 3][c];
        *(float4*)(out + ((size_t)b * CCH + c) * NN + n0 + 4 * q) = v;
    }
}

extern "C" void kernel_launch(void* const* d_in, const int* in_sizes, int n_in,
                              void* d_out, int out_size, void* d_ws, size_t ws_size,
                              hipStream_t stream) {
    (void)in_sizes; (void)n_in; (void)out_size; (void)ws_size;
    const float* x    = (const float*)d_in[0];
    const int*   edge = (const int*)d_in[1];
    const float* W    = (const float*)d_in[2];
    const float* bias = (const float*)d_in[3];
    float*       out  = (float*)d_out;
    _Float16*    y    = (_Float16*)d_ws;    // [B][N][128] fp16 = 8 MB

    gemm_kernel<<<dim3(256), dim3(256), 0, stream>>>(x, W, y);
    gather_kernel<<<dim3(1024), dim3(256), 0, stream>>>(y, edge, bias, out);
}

// Round 10
// 27.204 us; speedup vs baseline: 1.1868x; 1.1868x over previous
//
#include <hip/hip_runtime.h>

// EdgeConv2d: B=4, C=64, N=8192, K=16, C_OUT=64
// out[b,o,n] = relu( max_k ( y1[b, i1(b,n,k), o] + y2[b, i0(b,n,k), o] ) + bias[o] )
// y1 = (W[:,:C] - W[:,C:]) @ x[b],  y2 = W[:,C:] @ x[b]
// y (fp16): y[b][n][s], s<64 -> y1[s], s>=64 -> y2[s-64]. Row = 256 B.
// GEMM: fp16 LDS operands, k-pair interleaved, v_dot2_f32_f16 (round-8).
// Gather v5: r4's 2-line/instr pattern + register-resident indices
// (broadcast ds_read_b128 + cndmask select) + all 32 loads in flight.

#define BB   4
#define CCH  64
#define NN   8192
#define KK   16

typedef _Float16 h2  __attribute__((ext_vector_type(2)));
typedef _Float16 h8  __attribute__((ext_vector_type(8)));
typedef _Float16 h16 __attribute__((ext_vector_type(16)));
typedef int      v4i __attribute__((ext_vector_type(4)));

#if __has_builtin(__builtin_amdgcn_fdot2)
#define FDOT2(a, b, c) __builtin_amdgcn_fdot2((a), (b), (c), false)
#else
#define FDOT2(a, b, c) ((c) + (float)(a).x * (float)(b).x + (float)(a).y * (float)(b).y)
#endif

// ---------------------------------------------------------------------------
// Kernel 1: y GEMM (unchanged from round 8).
// ---------------------------------------------------------------------------
__global__ __launch_bounds__(256) void gemm_kernel(const float* __restrict__ x,
                                                   const float* __restrict__ W,
                                                   _Float16* __restrict__ y) {
    __shared__ _Float16 wT2[32 * 264];   // [kp][2s+p], s = 0..127 stacked chans
    __shared__ _Float16 xs2[32 * 264];   // [kp][2n+p], n = 0..127

    const int t   = threadIdx.x;
    const int blk = blockIdx.x;           // 256 = b(4) x ntile(64)
    const int b   = blk >> 6;
    const int n0  = (blk & 63) * 128;

    {
        const int k  = t & 63;
        const int kp = k >> 1, par = k & 1;
        const int sb = t >> 6;
        #pragma unroll
        for (int i = 0; i < 32; ++i) {
            const int s = sb + 4 * i;
            float v;
            if (s < CCH) v = W[s * 128 + k] - W[s * 128 + 64 + k];
            else         v = W[(s - CCH) * 128 + 64 + k];
            wT2[kp * 264 + 2 * s + par] = (_Float16)v;
        }
    }
    {
        const float* xb = x + (size_t)b * CCH * NN + n0;
        #pragma unroll
        for (int i = 0; i < 8; ++i) {
            const int k  = (t >> 5) + 8 * i;
            const int nq = (t & 31) * 4;
            const float4 v = *(const float4*)&xb[(size_t)k * NN + nq];
            const int kp = k >> 1, par = k & 1;
            _Float16* d = &xs2[kp * 264 + 2 * nq + par];
            d[0] = (_Float16)v.x; d[2] = (_Float16)v.y;
            d[4] = (_Float16)v.z; d[6] = (_Float16)v.w;
        }
    }
    __syncthreads();

    const int sg = t & 15;
    const int ng = t >> 4;
    const int s0 = sg * 8, nn0 = ng * 8;

    float acc[8][8];
    #pragma unroll
    for (int i = 0; i < 8; ++i)
        #pragma unroll
        for (int j = 0; j < 8; ++j) acc[i][j] = 0.f;

    #pragma unroll 2
    for (int kp = 0; kp < 32; ++kp) {
        const h16 wv = *(const h16*)&wT2[kp * 264 + 2 * s0];
        const h16 xv = *(const h16*)&xs2[kp * 264 + 2 * nn0];
        #pragma unroll
        for (int i = 0; i < 8; ++i) {
            h2 wp; wp.x = wv[2 * i]; wp.y = wv[2 * i + 1];
            #pragma unroll
            for (int j = 0; j < 8; ++j) {
                h2 xp; xp.x = xv[2 * j]; xp.y = xv[2 * j + 1];
                acc[i][j] = FDOT2(wp, xp, acc[i][j]);
            }
        }
    }

    _Float16* yb = y + ((size_t)b * NN + n0 + nn0) * 128 + s0;
    #pragma unroll
    for (int j = 0; j < 8; ++j) {
        h8 v;
        #pragma unroll
        for (int i = 0; i < 8; ++i) v[i] = (_Float16)acc[i][j];
        *(h8*)&yb[(size_t)j * 128] = v;
    }
}

// ---------------------------------------------------------------------------
// Kernel 2: gather v5. 2048 blocks x 256 thr; block = (b, 16-node tile).
// Per node: 8 broadcast ds_read_b128 bring both index rows into registers;
// 16 load-pair instructions (each 2 distinct 128 B lines, 32 lanes/line);
// in-lane pk_add/pk_max; one shfl_xor(32) fold; LDS-transposed store.
// ---------------------------------------------------------------------------
__global__ __launch_bounds__(256) void gather_kernel(const _Float16* __restrict__ y,
                                                     const int* __restrict__ edge,
                                                     const float* __restrict__ bias,
                                                     float* __restrict__ out) {
    __shared__ int   eL[16][2][16];   // [nl][src][k] src0=e1(center->y1), src1=e0(->y2)
    __shared__ float so[16][65];

    const int t   = threadIdx.x;
    const int blk = blockIdx.x;       // 2048
    const int xcd  = blk & 7;
    const int b    = xcd >> 1;
    const int tile = ((blk >> 3) << 1) | (xcd & 1);   // 0..511
    const int n0   = tile * 16;

    if (t < 128) {
        const int src = t >> 6;                 // 0 -> e1, 1 -> e0
        const int f   = (t & 63) << 2;
        const int nl  = f >> 4, k0 = f & 15;
        const size_t eb = (size_t)(src == 0 ? BB + b : b) * NN * KK;
        *(v4i*)&eL[nl][src][k0] = *(const v4i*)&edge[eb + (size_t)(n0 + nl) * KK + k0];
    }
    __syncthreads();

    const int w    = t >> 6;
    const int lane = t & 63;
    const int half = lane >> 5;       // which k of each pair
    const int cl   = lane & 31;       // channel pair: {2cl, 2cl+1}
    const bool hi  = (half != 0);

    const float2 bv = *(const float2*)&bias[2 * cl];
    const _Float16* yb = y + (size_t)b * NN * 128;
    const uint co1 = 2 * cl;          // y1 chan offset (fp16 elems)
    const uint co2 = 64 + 2 * cl;     // y2

    #pragma unroll
    for (int u = 0; u < 4; ++u) {
        const int nl = 4 * w + u;
        // Broadcast index rows into registers (wave-uniform addresses).
        const v4i e1a = *(const v4i*)&eL[nl][0][0];
        const v4i e1b = *(const v4i*)&eL[nl][0][4];
        const v4i e1c = *(const v4i*)&eL[nl][0][8];
        const v4i e1d = *(const v4i*)&eL[nl][0][12];
        const v4i e0a = *(const v4i*)&eL[nl][1][0];
        const v4i e0b = *(const v4i*)&eL[nl][1][4];
        const v4i e0c = *(const v4i*)&eL[nl][1][8];
        const v4i e0d = *(const v4i*)&eL[nl][1][12];

        h2 s[8];
        // s[kp] covers k = 2kp (half 0) / 2kp+1 (half 1). All 16 global
        // load-pairs are independent straight-line code -> stay in flight.
#define LOADP(E1, E0, S0, S1, DST)  {                                        \
        const int i1 = hi ? (E1).S1 : (E1).S0;                               \
        const int i0 = hi ? (E0).S1 : (E0).S0;                               \
        const uint aa = *(const uint*)&yb[(size_t)(uint)i1 * 128 + co1];     \
        const uint cc = *(const uint*)&yb[(size_t)(uint)i0 * 128 + co2];     \
        union { uint u32; h2 h; } ua_, uc_;  ua_.u32 = aa; uc_.u32 = cc;     \
        DST = ua_.h + uc_.h; }

        LOADP(e1a, e0a, x, y, s[0])
        LOADP(e1a, e0a, z, w, s[1])
        LOADP(e1b, e0b, x, y, s[2])
        LOADP(e1b, e0b, z, w, s[3])
        LOADP(e1c, e0c, x, y, s[4])
        LOADP(e1c, e0c, z, w, s[5])
        LOADP(e1d, e0d, x, y, s[6])
        LOADP(e1d, e0d, z, w, s[7])
#undef LOADP

        h2 m = s[0];
        #pragma unroll
        for (int kp = 1; kp < 8; ++kp) m = __builtin_elementwise_max(m, s[kp]);
        union { int i32; h2 h; } um, uo;
        um.h = m;
        uo.i32 = __shfl_xor(um.i32, 32, 64);
        m = __builtin_elementwise_max(m, uo.h);
        if (half == 0) {
            float2 r;
            r.x = fmaxf((float)m.x + bv.x, 0.f);
            r.y = fmaxf((float)m.y + bv.y, 0.f);
            *(float2*)&so[nl][2 * cl] = r;
        }
    }
    __syncthreads();

    {
        const int c = t >> 2;
        const int q = t & 3;
        float4 v;
        v.x = so[4 * q + 0][c];
        v.y = so[4 * q + 1][c];
        v.z = so[4 * q + 2][c];
        v.w = so[4 * q + 3][c];
        *(float4*)(out + ((size_t)b * CCH + c) * NN + n0 + 4 * q) = v;
    }
}

extern "C" void kernel_launch(void* const* d_in, const int* in_sizes, int n_in,
                              void* d_out, int out_size, void* d_ws, size_t ws_size,
                              hipStream_t stream) {
    (void)in_sizes; (void)n_in; (void)out_size; (void)ws_size;
    const float* x    = (const float*)d_in[0];
    const int*   edge = (const int*)d_in[1];
    const float* W    = (const float*)d_in[2];
    const float* bias = (const float*)d_in[3];
    float*       out  = (float*)d_out;
    _Float16*    y    = (_Float16*)d_ws;    // [B][N][128] fp16 = 8 MB

    gemm_kernel<<<dim3(256), dim3(256), 0, stream>>>(x, W, y);
    gather_kernel<<<dim3(2048), dim3(256), 0, stream>>>(y, edge, bias, out);
}